// Round 21
// baseline (95.287 us; speedup 1.0000x reference)
//
#include <hip/hip_runtime.h>
#include <math.h>

// Problem constants (fixed instance)
namespace {
constexpr int R_ = 32768;     // BS*N rows
constexpr int N_ = 16;
constexpr int NA_ = 30;
constexpr int BSB_ = R_ / N_; // 2048 batches
constexpr int NB64_ = R_ / 64; // 512 row-blocks (64 rows each)
}

typedef __bf16 bf16x8 __attribute__((ext_vector_type(8)));
typedef float f32x4 __attribute__((ext_vector_type(4)));

// Native bf16 convert (RTNE, bit-identical to manual round-to-nearest-even);
// compiler emits v_cvt_pk_bf16_f32 and fuses pairs (guide m240: don't hand-asm).
__device__ inline unsigned int f2bf(float f) {
    return (unsigned int)__builtin_bit_cast(unsigned short, (__bf16)f);
}
__device__ inline float bf2f(unsigned int us) {
    return __uint_as_float(us << 16);
}
__device__ inline unsigned int pack2(float a, float b) {
    return f2bf(a) | (f2bf(b) << 16);
}
__device__ inline uint4 pack8(float4 f0, float4 f1) {
    uint4 u;
    u.x = pack2(f0.x, f0.y); u.y = pack2(f0.z, f0.w);
    u.z = pack2(f1.x, f1.y); u.w = pack2(f1.z, f1.w);
    return u;
}
// Fast transcendentals (v_exp/v_rcp); rel err ~2^-21 << bf16 rounding 2^-9.
__device__ inline float fsig(float x)  { return __builtin_amdgcn_rcpf(1.f + __expf(-x)); }
__device__ inline float ftanh(float x) { return 1.f - 2.f * __builtin_amdgcn_rcpf(__expf(2.f * x) + 1.f); }

// A fragment from swizzled LDS tile (KC = 16B-chunks per row)
__device__ __forceinline__ bf16x8 lda_frag(const uint4* At, int KC, int row, int c) {
    return __builtin_bit_cast(bf16x8, At[(row * KC + c) ^ (row & 7)]);
}
// B fragment direct from global bf16 weights
__device__ __forceinline__ bf16x8 ldb_frag(const unsigned short* W, int row, int rstride, int c) {
    return __builtin_bit_cast(bf16x8, *(const uint4*)(W + (size_t)row * rstride + (size_t)c * 8));
}

// ---------------------------------------------------------------------------
// One-shot weight conversion f32 -> bf16 into workspace (concatenated).
namespace woff {
constexpr unsigned fc1 = 0;
constexpr unsigned ih  = 16384;
constexpr unsigned hh  = 65536;
constexpr unsigned l1  = 114688;
constexpr unsigned l2  = 122880;
constexpr unsigned m1  = 139264;
constexpr unsigned m2  = 204800;
constexpr unsigned kw  = 237568;
constexpr unsigned qw  = 241664;
constexpr unsigned v1  = 243712;
constexpr unsigned v2  = 292864;
constexpr unsigned f2  = 309248;
constexpr unsigned total = 347648;
}

__global__ __launch_bounds__(256)
void wcvt_kernel(const float* __restrict__ fc1_w, const float* __restrict__ w_ih,
                 const float* __restrict__ w_hh, const float* __restrict__ lse_w1,
                 const float* __restrict__ lse_w2, const float* __restrict__ me_w1,
                 const float* __restrict__ me_w2, const float* __restrict__ k_w,
                 const float* __restrict__ q_w, const float* __restrict__ v_w1,
                 const float* __restrict__ v_w2, const float* __restrict__ fc2_w,
                 unsigned short* __restrict__ dst)
{
    unsigned i = blockIdx.x * 256 + threadIdx.x;
    if (i >= woff::total) return;
    const float* src; unsigned base;
    if      (i < woff::ih) { src = fc1_w;  base = woff::fc1; }
    else if (i < woff::hh) { src = w_ih;   base = woff::ih; }
    else if (i < woff::l1) { src = w_hh;   base = woff::hh; }
    else if (i < woff::l2) { src = lse_w1; base = woff::l1; }
    else if (i < woff::m1) { src = lse_w2; base = woff::l2; }
    else if (i < woff::m2) { src = me_w1;  base = woff::m1; }
    else if (i < woff::kw) { src = me_w2;  base = woff::m2; }
    else if (i < woff::qw) { src = k_w;    base = woff::kw; }
    else if (i < woff::v1) { src = q_w;    base = woff::qw; }
    else if (i < woff::v2) { src = v_w1;   base = woff::v1; }
    else if (i < woff::f2) { src = v_w2;   base = woff::v2; }
    else                   { src = fc2_w;  base = woff::f2; }
    dst[i] = (unsigned short)f2bf(src[i - base]);
}

// ---------------------------------------------------------------------------
// Merged stage 1, 64-row tiles, 512 threads / 8 waves, wave w: 16-col strip
// with 4 row-fragments (B-frag reuse x4). (512,4): no spill (r16 verified).
// h and le bounced through dead LDS tiles -> coalesced uint4 stores.
__global__ __launch_bounds__(512, 4)
void stage1(const float* __restrict__ inputs, const float* __restrict__ hidden,
            const unsigned short* __restrict__ fc1w, const float* __restrict__ fc1_b,
            const unsigned short* __restrict__ wih, const unsigned short* __restrict__ whh,
            const float* __restrict__ b_ih, const float* __restrict__ b_hh,
            unsigned short* __restrict__ hb,
            const float* __restrict__ latent,
            const unsigned short* __restrict__ w1b, const float* __restrict__ b1,
            const unsigned short* __restrict__ w2b, const float* __restrict__ b2,
            unsigned short* __restrict__ leb)
{
    __shared__ uint4 shbuf[64 * 48];   // 48 KB, unioned between both paths
    const int tid = threadIdx.x;
    const int lane = tid & 63, w = tid >> 6;      // w: 0..7
    const int m = lane & 15, g = lane >> 4;

    if (blockIdx.x < (unsigned)NB64_) {
        // ================= fc1 + GRU =================
        uint4* Ain   = shbuf;            // 64x16: inputs bf16; later h bounce
        uint4* Atile = shbuf + 64 * 16;  // 64x32: [x | hidden] bf16
        const int r0 = blockIdx.x * 64;

        for (int idx = tid; idx < 64 * 16; idx += 512) {
            int row = idx >> 4, c = idx & 15;
            const float4* p = (const float4*)(inputs + (size_t)(r0 + row) * 128 + c * 8);
            Ain[(row * 16 + c) ^ (row & 7)] = pack8(p[0], p[1]);
            const float4* ph = (const float4*)(hidden + (size_t)(r0 + row) * 128 + c * 8);
            Atile[(row * 32 + (16 + c)) ^ (row & 7)] = pack8(ph[0], ph[1]);
        }
        __syncthreads();

        // ---- phase 1: x = relu(fc1); wave w: cols w*16..w*16+15, 64 rows ----
        {
            f32x4 acc[4] = {};
            #pragma unroll
            for (int ks = 0; ks < 4; ++ks) {
                bf16x8 bf = ldb_frag(fc1w, w * 16 + m, 128, ks * 4 + g);
                #pragma unroll
                for (int fr = 0; fr < 4; ++fr) {
                    bf16x8 af = lda_frag(Ain, 16, fr * 16 + m, ks * 4 + g);
                    acc[fr] = __builtin_amdgcn_mfma_f32_16x16x32_bf16(af, bf, acc[fr], 0, 0, 0);
                }
            }
            int col = w * 16 + m;
            float bv = fc1_b[col];
            int c = col >> 3, el = col & 7;
            #pragma unroll
            for (int fr = 0; fr < 4; ++fr) {
                #pragma unroll
                for (int i = 0; i < 4; ++i) {
                    int row = fr * 16 + g * 4 + i;
                    float v = acc[fr][i] + bv;
                    v = v > 0.f ? v : 0.f;
                    ((unsigned short*)Atile)[((row * 32 + c) ^ (row & 7)) * 8 + el] =
                        (unsigned short)f2bf(v);
                }
            }
        }
        __syncthreads();   // fc1 reads of Ain done; x visible in Atile

        // ---- phase 2: GRU; wave w: gate cols w*16..w*16+15, 64 rows ----
        {
            f32x4 rr[4] = {}, zz[4] = {}, ni[4] = {}, nh[4] = {};
            const int ro = w * 16 + m;
            #pragma unroll
            for (int ks = 0; ks < 4; ++ks) {  // x part: wih
                bf16x8 brr = ldb_frag(wih, ro, 128, ks * 4 + g);
                bf16x8 bzz = ldb_frag(wih, 128 + ro, 128, ks * 4 + g);
                bf16x8 bnn = ldb_frag(wih, 256 + ro, 128, ks * 4 + g);
                #pragma unroll
                for (int fr = 0; fr < 4; ++fr) {
                    bf16x8 af = lda_frag(Atile, 32, fr * 16 + m, ks * 4 + g);
                    rr[fr] = __builtin_amdgcn_mfma_f32_16x16x32_bf16(af, brr, rr[fr], 0, 0, 0);
                    zz[fr] = __builtin_amdgcn_mfma_f32_16x16x32_bf16(af, bzz, zz[fr], 0, 0, 0);
                    ni[fr] = __builtin_amdgcn_mfma_f32_16x16x32_bf16(af, bnn, ni[fr], 0, 0, 0);
                }
            }
            #pragma unroll
            for (int ks = 0; ks < 4; ++ks) {  // hidden part: whh
                bf16x8 brr = ldb_frag(whh, ro, 128, ks * 4 + g);
                bf16x8 bzz = ldb_frag(whh, 128 + ro, 128, ks * 4 + g);
                bf16x8 bnn = ldb_frag(whh, 256 + ro, 128, ks * 4 + g);
                #pragma unroll
                for (int fr = 0; fr < 4; ++fr) {
                    bf16x8 af = lda_frag(Atile, 32, fr * 16 + m, 16 + ks * 4 + g);
                    rr[fr] = __builtin_amdgcn_mfma_f32_16x16x32_bf16(af, brr, rr[fr], 0, 0, 0);
                    zz[fr] = __builtin_amdgcn_mfma_f32_16x16x32_bf16(af, bzz, zz[fr], 0, 0, 0);
                    nh[fr] = __builtin_amdgcn_mfma_f32_16x16x32_bf16(af, bnn, nh[fr], 0, 0, 0);
                }
            }
            {
                int c = ro;   // 0..127
                float brz = b_ih[c] + b_hh[c];
                float bzz2 = b_ih[128 + c] + b_hh[128 + c];
                float bin = b_ih[256 + c], bhn = b_hh[256 + c];
                int hc = 16 + (c >> 3), hel = c & 7;  // hidden chunk in Atile
                unsigned short* hbounce = (unsigned short*)Ain;   // Ain dead
                #pragma unroll
                for (int fr = 0; fr < 4; ++fr) {
                    #pragma unroll
                    for (int i = 0; i < 4; ++i) {
                        int row = fr * 16 + g * 4 + i;
                        float rv = fsig(rr[fr][i] + brz);
                        float zv = fsig(zz[fr][i] + bzz2);
                        float ng = ftanh(ni[fr][i] + bin + rv * (nh[fr][i] + bhn));
                        float hp = bf2f(((unsigned short*)Atile)[((row * 32 + hc) ^ (row & 7)) * 8 + hel]);
                        float hv = ng + zv * (hp - ng);
                        hbounce[row * 128 + c] = (unsigned short)f2bf(hv);
                    }
                }
            }
        }
        __syncthreads();
        for (int idx = tid; idx < 64 * 16; idx += 512) {  // coalesced h store
            int row = idx >> 4, c = idx & 15;
            *(uint4*)(hb + (size_t)(r0 + row) * 128 + c * 8) = Ain[idx];
        }
    } else {
        // ================= lse1 + lse2 =================
        uint4* Alat = shbuf;            // 64x8
        uint4* Alt  = shbuf + 64 * 8;   // 64x16: lt; later le bounce
        const int r0 = (blockIdx.x - NB64_) * 64;

        {   // 512 items, one per thread
            int row = tid >> 3, c = tid & 7;
            const float4* p = (const float4*)(latent + (size_t)(r0 + row) * 64 + c * 8);
            Alat[(row * 8 + c) ^ (row & 7)] = pack8(p[0], p[1]);
        }
        __syncthreads();

        // lse1: K=64, O=128; wave w: cols w*16 -> Alt
        {
            f32x4 acc[4] = {};
            #pragma unroll
            for (int ks = 0; ks < 2; ++ks) {
                bf16x8 bf = ldb_frag(w1b, w * 16 + m, 64, ks * 4 + g);
                #pragma unroll
                for (int fr = 0; fr < 4; ++fr) {
                    bf16x8 af = lda_frag(Alat, 8, fr * 16 + m, ks * 4 + g);
                    acc[fr] = __builtin_amdgcn_mfma_f32_16x16x32_bf16(af, bf, acc[fr], 0, 0, 0);
                }
            }
            int col = w * 16 + m;
            float bv = b1[col];
            int c = col >> 3, el = col & 7;
            #pragma unroll
            for (int fr = 0; fr < 4; ++fr) {
                #pragma unroll
                for (int i = 0; i < 4; ++i) {
                    int row = fr * 16 + g * 4 + i;
                    float v = acc[fr][i] + bv;
                    v = v > 0.f ? v : 0.f;
                    ((unsigned short*)Alt)[((row * 16 + c) ^ (row & 7)) * 8 + el] =
                        (unsigned short)f2bf(v);
                }
            }
        }
        __syncthreads();

        // lse2: K=128, O=128 -> le bounced through Alt (dead after reads)
        {
            f32x4 acc[4] = {};
            #pragma unroll
            for (int ks = 0; ks < 4; ++ks) {
                bf16x8 bf = ldb_frag(w2b, w * 16 + m, 128, ks * 4 + g);
                #pragma unroll
                for (int fr = 0; fr < 4; ++fr) {
                    bf16x8 af = lda_frag(Alt, 16, fr * 16 + m, ks * 4 + g);
                    acc[fr] = __builtin_amdgcn_mfma_f32_16x16x32_bf16(af, bf, acc[fr], 0, 0, 0);
                }
            }
            __syncthreads();   // all lse2 reads of Alt done
            int col = w * 16 + m;
            float bv = b2[col];
            unsigned short* lebounce = (unsigned short*)Alt;
            #pragma unroll
            for (int fr = 0; fr < 4; ++fr) {
                #pragma unroll
                for (int i = 0; i < 4; ++i) {
                    int rowl = fr * 16 + g * 4 + i;
                    float v = acc[fr][i] + bv;
                    lebounce[rowl * 128 + col] = (unsigned short)f2bf(v);
                }
            }
        }
        __syncthreads();
        for (int idx = tid; idx < 64 * 16; idx += 512) {  // coalesced le store
            int row = idx >> 4, c = idx & 15;
            *(uint4*)(leb + (size_t)(r0 + row) * 128 + c * 8) = Alt[idx];
        }
    }
}

// ---------------------------------------------------------------------------
// me1 GEMM (K=256, O=256) + BN partials + fused hl, 64-row blocks, 512 thr.
__global__ __launch_bounds__(512, 4)
void me1_stats(const unsigned short* __restrict__ hb, const unsigned short* __restrict__ leb,
               const unsigned short* __restrict__ W, const float* __restrict__ bias,
               const unsigned short* __restrict__ f2w, const float* __restrict__ fc2_b,
               unsigned short* __restrict__ t1,
               float* __restrict__ psum, float* __restrict__ psq,
               float* __restrict__ hl)
{
    __shared__ uint4 Atile[64 * 32];   // 32 KB: [h | le]
    __shared__ uint4 T1b[64 * 32];     // 32 KB: t1 bounce (linear 64x256 bf16)
    const int tid = threadIdx.x;
    const int r0 = blockIdx.x * 64;

    for (int idx = tid; idx < 64 * 16; idx += 512) {
        int row = idx >> 4, c = idx & 15;
        Atile[(row * 32 + c) ^ (row & 7)] =
            *(const uint4*)(hb + (size_t)(r0 + row) * 128 + c * 8);
        Atile[(row * 32 + (16 + c)) ^ (row & 7)] =
            *(const uint4*)(leb + (size_t)(r0 + row) * 128 + c * 8);
    }
    __syncthreads();

    const int lane = tid & 63, w = tid >> 6;
    const int m = lane & 15, g = lane >> 4;
    unsigned short* t1s = (unsigned short*)T1b;

    {
        const int o0 = w * 32;
        f32x4 acc[4][2] = {};
        #pragma unroll
        for (int ks = 0; ks < 8; ++ks) {
            bf16x8 bf[2];
            #pragma unroll
            for (int fc = 0; fc < 2; ++fc)
                bf[fc] = ldb_frag(W, o0 + fc * 16 + m, 256, ks * 4 + g);
            #pragma unroll
            for (int fr = 0; fr < 4; ++fr) {
                bf16x8 af = lda_frag(Atile, 32, fr * 16 + m, ks * 4 + g);
                #pragma unroll
                for (int fc = 0; fc < 2; ++fc)
                    acc[fr][fc] = __builtin_amdgcn_mfma_f32_16x16x32_bf16(
                        af, bf[fc], acc[fr][fc], 0, 0, 0);
            }
        }
        #pragma unroll
        for (int fc = 0; fc < 2; ++fc) {
            int col = o0 + fc * 16 + m;
            float bv = bias[col];
            float s = 0.f, q = 0.f;
            #pragma unroll
            for (int fr = 0; fr < 4; ++fr) {
                #pragma unroll
                for (int i = 0; i < 4; ++i) {
                    int rowl = fr * 16 + g * 4 + i;
                    float v = acc[fr][fc][i] + bv;
                    t1s[rowl * 256 + col] = (unsigned short)f2bf(v);
                    s += v; q += v * v;
                }
            }
            s += __shfl_xor(s, 16); s += __shfl_xor(s, 32);  // over g: all 64 rows
            q += __shfl_xor(q, 16); q += __shfl_xor(q, 32);
            if (lane < 16) {
                psum[(size_t)blockIdx.x * 256 + col] = s;
                psq[(size_t)blockIdx.x * 256 + col] = q;
            }
        }
    }
    __syncthreads();
    for (int idx = tid; idx < 64 * 32; idx += 512) {  // coalesced t1 store
        int row = idx >> 5, c = idx & 31;
        *(uint4*)(t1 + (size_t)(r0 + row) * 256 + c * 8) = T1b[row * 32 + c];
    }

    // ---- fused hl: waves 0-3, rows w*16..w*16+15, cols 0..29 ----
    if (w < 4) {
        f32x4 acc[2] = {};
        #pragma unroll
        for (int ks = 0; ks < 8; ++ks) {
            bf16x8 af = lda_frag(Atile, 32, w * 16 + m, ks * 4 + g);
            bf16x8 bf[2];
            #pragma unroll
            for (int fc = 0; fc < 2; ++fc) {
                int col = fc * 16 + m;
                bf[fc] = (col < NA_) ? ldb_frag(f2w, col, 1280, ks * 4 + g) : bf16x8{};
            }
            #pragma unroll
            for (int fc = 0; fc < 2; ++fc)
                acc[fc] = __builtin_amdgcn_mfma_f32_16x16x32_bf16(af, bf[fc], acc[fc], 0, 0, 0);
        }
        #pragma unroll
        for (int fc = 0; fc < 2; ++fc) {
            int col = fc * 16 + m;
            if (col < NA_) {
                float bv = fc2_b[col];
                #pragma unroll
                for (int i = 0; i < 4; ++i) {
                    int row = r0 + w * 16 + g * 4 + i;
                    hl[(size_t)row * NA_ + col] = acc[fc][i] + bv;
                }
            }
        }
    }
}

// ---------------------------------------------------------------------------
// Parallel BN finalize: one block per feature; threads stride over NB64_.
__global__ __launch_bounds__(256)
void bn_final_kernel(const float* __restrict__ psum, const float* __restrict__ psq,
                     const float* __restrict__ g, const float* __restrict__ beta,
                     float* __restrict__ scale, float* __restrict__ shift)
{
    __shared__ float redS[4], redQ[4];
    const int f = blockIdx.x;
    const int tid = threadIdx.x;
    float s = 0.f, q = 0.f;
    for (int b = tid; b < NB64_; b += 256) {
        s += psum[(size_t)b * 256 + f];
        q += psq[(size_t)b * 256 + f];
    }
    #pragma unroll
    for (int off = 32; off >= 1; off >>= 1) {
        s += __shfl_down(s, off);
        q += __shfl_down(q, off);
    }
    if ((tid & 63) == 0) { redS[tid >> 6] = s; redQ[tid >> 6] = q; }
    __syncthreads();
    if (tid == 0) {
        s = redS[0] + redS[1] + redS[2] + redS[3];
        q = redQ[0] + redQ[1] + redQ[2] + redQ[3];
        float mean = s / (float)R_;
        float var = q / (float)R_ - mean * mean;
        float istd = rsqrtf(var + 1e-5f);
        float sc = g[f] * istd;
        scale[f] = sc;
        shift[f] = beta[f] - mean * sc;
    }
}

// ---------------------------------------------------------------------------
// Fused me2 + kq_norm + v1 + v2, 64-row blocks, 512 threads / 8 waves.
// kh/qh stored as bf16 (halves kq traffic; unit-norm vectors, error << thr).
__global__ __launch_bounds__(512, 4)
void me2kqv(const unsigned short* __restrict__ t1,
            const float* __restrict__ scale, const float* __restrict__ shift,
            const unsigned short* __restrict__ W2, const float* __restrict__ me2_b,
            const float* __restrict__ eps,
            const unsigned short* __restrict__ hb,
            const unsigned short* __restrict__ kwb, const float* __restrict__ k_b,
            const unsigned short* __restrict__ qwb, const float* __restrict__ q_b,
            const unsigned short* __restrict__ v1w, const float* __restrict__ v1_b,
            const unsigned short* __restrict__ v2w, const float* __restrict__ v2_b,
            unsigned short* __restrict__ kh, unsigned short* __restrict__ qh,
            unsigned short* __restrict__ valb)
{
    __shared__ uint4 bufA[64 * 32];   // 32 KB: t1(BN) -> mean scratch -> A3 (t3)
    __shared__ uint4 bufB[64 * 24];   // 24 KB: [h 0..15 | pm 16..23] -> val bounce
    __shared__ float sc_s[256], sh_s[256];
    const int tid = threadIdx.x;
    const int r0 = blockIdx.x * 64;
    const int lane = tid & 63, w = tid >> 6;   // w: 0..7
    const int m = lane & 15, g = lane >> 4;

    if (tid < 256) { sc_s[tid] = scale[tid]; sh_s[tid] = shift[tid]; }
    for (int idx = tid; idx < 64 * 16; idx += 512) {
        int row = idx >> 4, c = idx & 15;
        bufB[(row * 24 + c) ^ (row & 7)] =
            *(const uint4*)(hb + (size_t)(r0 + row) * 128 + c * 8);
    }
    __syncthreads();

    // stage t1 with BN(scale/shift)+lrelu -> bufA (swizzled)
    for (int idx = tid; idx < 64 * 32; idx += 512) {
        int row = idx >> 5, c = idx & 31;
        uint4 u = *(const uint4*)(t1 + (size_t)(r0 + row) * 256 + c * 8);
        unsigned int vv[4] = {u.x, u.y, u.z, u.w};
        float f[8];
        #pragma unroll
        for (int q2 = 0; q2 < 4; ++q2) {
            f[2 * q2]     = __uint_as_float((vv[q2] & 0xffffu) << 16);
            f[2 * q2 + 1] = __uint_as_float(vv[q2] & 0xffff0000u);
        }
        int k = c * 8;
        #pragma unroll
        for (int j = 0; j < 8; ++j) {
            float v = f[j] * sc_s[k + j] + sh_s[k + j];
            f[j] = v > 0.f ? v : 0.01f * v;
        }
        uint4 r;
        r.x = pack2(f[0], f[1]); r.y = pack2(f[2], f[3]);
        r.z = pack2(f[4], f[5]); r.w = pack2(f[6], f[7]);
        bufA[(row * 32 + c) ^ (row & 7)] = r;
    }
    __syncthreads();

    // ---- me2 GEMM: wave w owns output col w*16+m (0..127); 4 row frags ----
    {
        const int colm = w * 16 + m;       // 0..63 mean, 64..127 std
        f32x4 acc[4] = {};
        #pragma unroll
        for (int ks = 0; ks < 8; ++ks) {
            bf16x8 bf = ldb_frag(W2, colm, 256, ks * 4 + g);
            #pragma unroll
            for (int fr = 0; fr < 4; ++fr) {
                bf16x8 af = lda_frag(bufA, 32, fr * 16 + m, ks * 4 + g);
                acc[fr] = __builtin_amdgcn_mfma_f32_16x16x32_bf16(af, bf, acc[fr], 0, 0, 0);
            }
        }
        float bv = me2_b[colm];
        __syncthreads();   // all bufA (t1) reads done; reuse as f32 mean scratch
        float* meanS = (float*)bufA;       // [64][64] f32
        if (w < 4) {       // mean cols: clip(lrelu(.)) -> scratch
            #pragma unroll
            for (int fr = 0; fr < 4; ++fr) {
                #pragma unroll
                for (int i = 0; i < 4; ++i) {
                    int row = fr * 16 + g * 4 + i;
                    float vm = acc[fr][i] + bv;
                    vm = vm > 0.f ? vm : 0.01f * vm;
                    vm = fminf(fmaxf(vm, -1.f), 1.f);
                    meanS[row * 64 + colm] = vm;
                }
            }
        }
        __syncthreads();
        if (w >= 4) {      // std cols: combine with mean + eps -> pm in bufB
            int cp = colm - 64;            // 0..63
            int hc = 16 + (cp >> 3), hel = cp & 7;
            #pragma unroll
            for (int fr = 0; fr < 4; ++fr) {
                #pragma unroll
                for (int i = 0; i < 4; ++i) {
                    int row = fr * 16 + g * 4 + i;
                    float vs = acc[fr][i] + bv;
                    vs = vs > 0.f ? vs : 0.01f * vs;
                    vs = fminf(fmaxf(vs, 0.5f), 1.f);
                    float e = eps[(size_t)(r0 + row) * 64 + cp];
                    float vm = meanS[row * 64 + cp];
                    ((unsigned short*)bufB)[((row * 24 + hc) ^ (row & 7)) * 8 + hel] =
                        (unsigned short)f2bf(vm + vs * e);
                }
            }
        }
    }
    __syncthreads();   // pm visible in bufB; meanS consumed (bufA free for A3)

    // ---- kq-norm: waves 0-3. w0: kh rows 0-31, w1: kh rows 32-63,
    //      w2: qh rows 0-31, w3: qh rows 32-63. Store bf16.
    if (w < 4) {
        const bool isq = (w >= 2);
        const int rbase = (w & 1) * 32;
        f32x4 acc[2][2] = {};
        const int nks = isq ? 2 : 4;
        for (int ks = 0; ks < nks; ++ks) {
            bf16x8 af[2], bf[2];
            #pragma unroll
            for (int fr = 0; fr < 2; ++fr)
                af[fr] = lda_frag(bufB, 24, rbase + fr * 16 + m, (isq ? 16 : 0) + ks * 4 + g);
            #pragma unroll
            for (int fc = 0; fc < 2; ++fc)
                bf[fc] = isq ? ldb_frag(qwb, fc * 16 + m, 64, ks * 4 + g)
                             : ldb_frag(kwb, fc * 16 + m, 128, ks * 4 + g);
            #pragma unroll
            for (int fr = 0; fr < 2; ++fr)
                #pragma unroll
                for (int fc = 0; fc < 2; ++fc)
                    acc[fr][fc] = __builtin_amdgcn_mfma_f32_16x16x32_bf16(
                        af[fr], bf[fc], acc[fr][fc], 0, 0, 0);
        }
        const float* bias = isq ? q_b : k_b;
        float b0 = bias[m], b1 = bias[16 + m];
        unsigned short* outp = isq ? qh : kh;
        #pragma unroll
        for (int fr = 0; fr < 2; ++fr) {
            #pragma unroll
            for (int i = 0; i < 4; ++i) {
                float v0 = acc[fr][0][i] + b0;
                float v1 = acc[fr][1][i] + b1;
                float ss = v0 * v0 + v1 * v1;
                ss += __shfl_xor(ss, 1); ss += __shfl_xor(ss, 2);
                ss += __shfl_xor(ss, 4); ss += __shfl_xor(ss, 8);
                float inv = 1.f / fmaxf(sqrtf(ss), 1e-8f);
                int row = r0 + rbase + fr * 16 + g * 4 + i;
                outp[(size_t)row * 32 + m] = (unsigned short)f2bf(v0 * inv);
                outp[(size_t)row * 32 + 16 + m] = (unsigned short)f2bf(v1 * inv);
            }
        }
    }

    // ---- v1 (K=192, O=256): 8 waves x 32 cols, 4 row frags -> bufA as A3 ----
    {
        const int o0 = w * 32;
        f32x4 acc[4][2] = {};
        #pragma unroll
        for (int ks = 0; ks < 6; ++ks) {
            bf16x8 bf[2];
            #pragma unroll
            for (int fc = 0; fc < 2; ++fc)
                bf[fc] = ldb_frag(v1w, o0 + fc * 16 + m, 192, ks * 4 + g);
            #pragma unroll
            for (int fr = 0; fr < 4; ++fr) {
                bf16x8 af = lda_frag(bufB, 24, fr * 16 + m, ks * 4 + g);
                #pragma unroll
                for (int fc = 0; fc < 2; ++fc)
                    acc[fr][fc] = __builtin_amdgcn_mfma_f32_16x16x32_bf16(
                        af, bf[fc], acc[fr][fc], 0, 0, 0);
            }
        }
        #pragma unroll
        for (int fc = 0; fc < 2; ++fc) {
            int col = o0 + fc * 16 + m;
            float bv = v1_b[col];
            int c = col >> 3, el = col & 7;
            #pragma unroll
            for (int fr = 0; fr < 4; ++fr) {
                #pragma unroll
                for (int i = 0; i < 4; ++i) {
                    int row = fr * 16 + g * 4 + i;
                    float v = acc[fr][fc][i] + bv;
                    v = v > 0.f ? v : 0.01f * v;
                    ((unsigned short*)bufA)[((row * 32 + c) ^ (row & 7)) * 8 + el] =
                        (unsigned short)f2bf(v);
                }
            }
        }
    }
    __syncthreads();

    // ---- v2 (K=256, O=64): wave w: col (w&3)*16+m, rows (w>>2)*32.. ----
    {
        const int col = (w & 3) * 16 + m;
        const int rbase = (w >> 2) * 32;
        f32x4 acc[2] = {};
        #pragma unroll
        for (int ks = 0; ks < 8; ++ks) {
            bf16x8 bf = ldb_frag(v2w, col, 256, ks * 4 + g);
            #pragma unroll
            for (int fr = 0; fr < 2; ++fr) {
                bf16x8 af = lda_frag(bufA, 32, rbase + fr * 16 + m, ks * 4 + g);
                acc[fr] = __builtin_amdgcn_mfma_f32_16x16x32_bf16(af, bf, acc[fr], 0, 0, 0);
            }
        }
        float bv = v2_b[col];
        unsigned short* vb = (unsigned short*)bufB;  // bufB dead after v1
        #pragma unroll
        for (int fr = 0; fr < 2; ++fr) {
            #pragma unroll
            for (int i = 0; i < 4; ++i) {
                int rowl = rbase + fr * 16 + g * 4 + i;
                vb[rowl * 64 + col] = (unsigned short)f2bf(acc[fr][i] + bv);
            }
        }
    }
    __syncthreads();
    {   // 64x64 bf16 = 512 uint4: one per thread
        int row = tid >> 3, c = tid & 7;
        *(uint4*)(valb + (size_t)(r0 + row) * 64 + c * 8) = ((uint4*)bufB)[row * 8 + c];
    }
}

// ---------------------------------------------------------------------------
// MFMA-ized tail: logits+softmax (1 MFMA/batch) + vproj (4 MFMA/agent, bf16
// w2 slice from L2) + combine -> out. 8 batches (128 rows) per block.
__global__ __launch_bounds__(512, 4)
void attn_tail(const unsigned short* __restrict__ khb, const unsigned short* __restrict__ qhb,
               const unsigned short* __restrict__ valb,
               const unsigned short* __restrict__ f2wb,   // bf16 fc2_w, stride 1280
               const float* __restrict__ hl, float* __restrict__ outv)
{
    __shared__ uint4 vt[136 * 8];        // value transposed by agent: [j*8+bi][8 chunks]
    __shared__ float al[128 * 16];       // alpha[row in block][j]
    __shared__ float vp[128 * 32];       // vproj[(j*8+bi)][na]
    const int tid = threadIdx.x;
    const int b0 = blockIdx.x * 8;       // first batch
    const size_t r0 = (size_t)b0 * 16;   // first row
    const int lane = tid & 63, w = tid >> 6;   // w: 0..7
    const int m = lane & 15, g = lane >> 4;

    // stage value transposed: src row r = bi*16 + j  ->  vt row j*8 + bi
    for (int idx = tid; idx < 128 * 8; idx += 512) {
        int r = idx >> 3, c = idx & 7;
        int bi = r >> 4, j = r & 15;
        int vr = j * 8 + bi;
        vt[(vr * 8 + c) ^ (vr & 7)] = *(const uint4*)(valb + (r0 + r) * 64 + c * 8);
    }

    // logits via MFMA: wave w handles batch b0+w. A=kh rows, B=qh rows (K=32).
    {
        bf16x8 af = ldb_frag(khb, (b0 + w) * 16 + m, 32, g);
        bf16x8 bf = ldb_frag(qhb, (b0 + w) * 16 + m, 32, g);
        f32x4 acc = {};
        acc = __builtin_amdgcn_mfma_f32_16x16x32_bf16(af, bf, acc, 0, 0, 0);
        // lane(m,g) holds logits[i' = g*4+i][j' = m]
        #pragma unroll
        for (int i = 0; i < 4; ++i) {
            float l = acc[i];
            float mx = l;
            #pragma unroll
            for (int mm = 8; mm >= 1; mm >>= 1) mx = fmaxf(mx, __shfl_xor(mx, mm));
            float e = __expf(l - mx);
            float s = e;
            #pragma unroll
            for (int mm = 8; mm >= 1; mm >>= 1) s += __shfl_xor(s, mm);
            float a = e / s;
            int ip = g * 4 + i;
            if (ip == m) a = 0.f;
            al[(w * 16 + ip) * 16 + m] = a;
        }
    }
    __syncthreads();

    // vproj via MFMA: wave w handles agents j = w and j = w+8.
    #pragma unroll
    for (int jj = 0; jj < 2; ++jj) {
        int j = w + jj * 8;
        f32x4 acc[2] = {};
        #pragma unroll
        for (int ks = 0; ks < 2; ++ks) {
            bf16x8 af = lda_frag(vt, 8, j * 8 + (m & 7), ks * 4 + g);
            #pragma unroll
            for (int fc = 0; fc < 2; ++fc) {
                bf16x8 bf = ldb_frag(f2wb, fc * 16 + m, 1280, 32 + j * 8 + ks * 4 + g);
                acc[fc] = __builtin_amdgcn_mfma_f32_16x16x32_bf16(af, bf, acc[fc], 0, 0, 0);
            }
        }
        #pragma unroll
        for (int fc = 0; fc < 2; ++fc) {
            int na = fc * 16 + m;
            if (na < NA_) {
                #pragma unroll
                for (int i = 0; i < 4; ++i) {
                    int bi = g * 4 + i;
                    if (bi < 8) vp[(j * 8 + bi) * 32 + na] = acc[fc][i];
                }
            }
        }
    }
    __syncthreads();

    // combine: out[r0+row][na] = hl + sum_j al[row][j] * vp[j*8+bi][na]
    for (int task = tid; task < 128 * NA_; task += 512) {
        int row = task / NA_, na = task - row * NA_;
        int bi = row >> 4;
        float acc = hl[(r0 + row) * NA_ + na];
        #pragma unroll
        for (int j = 0; j < 16; ++j)
            acc = fmaf(al[row * 16 + j], vp[(j * 8 + bi) * 32 + na], acc);
        outv[(r0 + row) * NA_ + na] = acc;
    }
}

extern "C" void kernel_launch(void* const* d_in, const int* in_sizes, int n_in,
                              void* d_out, int out_size, void* d_ws, size_t ws_size,
                              hipStream_t stream)
{
    (void)in_sizes; (void)n_in; (void)out_size; (void)ws_size;
    const float* inputs  = (const float*)d_in[0];
    const float* hidden  = (const float*)d_in[1];
    const float* latent  = (const float*)d_in[2];
    const float* eps     = (const float*)d_in[3];
    const float* fc1_w   = (const float*)d_in[4];
    const float* fc1_b   = (const float*)d_in[5];
    const float* w_ih    = (const float*)d_in[6];
    const float* w_hh    = (const float*)d_in[7];
    const float* b_ih    = (const float*)d_in[8];
    const float* b_hh    = (const float*)d_in[9];
    const float* lse_w1  = (const float*)d_in[10];
    const float* lse_b1  = (const float*)d_in[11];
    const float* lse_w2  = (const float*)d_in[12];
    const float* lse_b2  = (const float*)d_in[13];
    const float* me_w1   = (const float*)d_in[14];
    const float* me_b1   = (const float*)d_in[15];
    const float* me_g    = (const float*)d_in[16];
    const float* me_beta = (const float*)d_in[17];
    const float* me_w2   = (const float*)d_in[18];
    const float* me_b2   = (const float*)d_in[19];
    const float* k_w     = (const float*)d_in[20];
    const float* k_b     = (const float*)d_in[21];
    const float* q_w     = (const float*)d_in[22];
    const float* q_b     = (const float*)d_in[23];
    const float* v_w1    = (const float*)d_in[24];
    const float* v_b1    = (const float*)d_in[25];
    const float* v_w2    = (const float*)d_in[26];
    const float* v_b2    = (const float*)d_in[27];
    const float* fc2_w   = (const float*)d_in[28];
    const float* fc2_b   = (const float*)d_in[29];

    const size_t R = R_;
    // Workspace layout: bf16 activations, bf16 weights, then f32 buffers.
    unsigned short* bws = (unsigned short*)d_ws;
    unsigned short* hb   = bws;               // R*128
    unsigned short* leb  = hb + R * 128;      // R*128
    unsigned short* t1b  = leb + R * 128;     // R*256
    unsigned short* valb = t1b + R * 256;     // R*64
    unsigned short* khb  = valb + R * 64;     // R*32 (bf16)
    unsigned short* qhb  = khb + R * 32;      // R*32 (bf16)
    unsigned short* wb   = qhb + R * 32;      // 347648 (bf16 weights)
    float* fws  = (float*)(wb + woff::total);
    float* hlf  = fws;                 // R*30
    float* psum = hlf + R * 30;        // NB64_*256
    float* psq  = psum + (size_t)NB64_ * 256;
    float* scale = psq + (size_t)NB64_ * 256;
    float* shift = scale + 256;

    dim3 blk(256);
    dim3 g512(NB64_);

    // 0) weights -> bf16 (once per call; cheap)
    wcvt_kernel<<<dim3((woff::total + 255) / 256), blk, 0, stream>>>(
        fc1_w, w_ih, w_hh, lse_w1, lse_w2, me_w1, me_w2, k_w, q_w, v_w1, v_w2, fc2_w, wb);

    // 1) merged stage1 (64-row, 512 thr): fc1+GRU (0..511), lse1+lse2 (512..1023)
    stage1<<<dim3(2 * NB64_), dim3(512), 0, stream>>>(
        inputs, hidden, wb + woff::fc1, fc1_b, wb + woff::ih, wb + woff::hh,
        b_ih, b_hh, hb,
        latent, wb + woff::l1, lse_b1, wb + woff::l2, lse_b2, leb);
    // 2) t1 = me1(cat(h,le)) + BN partials + hl (64-row, 512 thr)
    me1_stats<<<g512, dim3(512), 0, stream>>>(hb, leb, wb + woff::m1, me_b1,
                                              wb + woff::f2, fc2_b, t1b, psum, psq, hlf);
    // 2b) BN finalize (parallel: one block per feature)
    bn_final_kernel<<<dim3(256), blk, 0, stream>>>(psum, psq, me_g, me_beta, scale, shift);
    // 3) fused me2 -> pm [LDS] -> kq_norm + v1 + v2 (64-row, 512 thr)
    me2kqv<<<g512, dim3(512), 0, stream>>>(t1b, scale, shift, wb + woff::m2, me_b2, eps,
                                           hb, wb + woff::kw, k_b, wb + woff::qw, q_b,
                                           wb + woff::v1, v_b1, wb + woff::v2, v_b2,
                                           khb, qhb, valb);
    // 4) MFMA-ized tail: logits+softmax + vproj + combine -> out (8 batches/block)
    attn_tail<<<dim3(BSB_ / 8), dim3(512), 0, stream>>>(
        khb, qhb, valb, wb + woff::f2, hlf, (float*)d_out);
}

// Round 22
// 94.268 us; speedup vs baseline: 1.0108x; 1.0108x over previous
//
#include <hip/hip_runtime.h>
#include <math.h>

// Problem constants (fixed instance)
namespace {
constexpr int R_ = 32768;     // BS*N rows
constexpr int N_ = 16;
constexpr int NA_ = 30;
constexpr int BSB_ = R_ / N_; // 2048 batches
constexpr int NB64_ = R_ / 64; // 512 row-blocks (64 rows each)
}

typedef __bf16 bf16x8 __attribute__((ext_vector_type(8)));
typedef float f32x4 __attribute__((ext_vector_type(4)));

__device__ inline unsigned int f2bf(float f) {
    unsigned int u = __float_as_uint(f);
    return (u + 0x7fffu + ((u >> 16) & 1u)) >> 16;  // RTN-even
}
__device__ inline float bf2f(unsigned int us) {
    return __uint_as_float(us << 16);
}
__device__ inline unsigned int pack2(float a, float b) {
    return f2bf(a) | (f2bf(b) << 16);
}
__device__ inline uint4 pack8(float4 f0, float4 f1) {
    uint4 u;
    u.x = pack2(f0.x, f0.y); u.y = pack2(f0.z, f0.w);
    u.z = pack2(f1.x, f1.y); u.w = pack2(f1.z, f1.w);
    return u;
}
// Fast transcendentals (v_exp/v_rcp); rel err ~2^-21 << bf16 rounding 2^-9.
__device__ inline float fsig(float x)  { return __builtin_amdgcn_rcpf(1.f + __expf(-x)); }
__device__ inline float ftanh(float x) { return 1.f - 2.f * __builtin_amdgcn_rcpf(__expf(2.f * x) + 1.f); }

// A fragment from swizzled LDS tile (KC = 16B-chunks per row)
__device__ __forceinline__ bf16x8 lda_frag(const uint4* At, int KC, int row, int c) {
    return __builtin_bit_cast(bf16x8, At[(row * KC + c) ^ (row & 7)]);
}
// B fragment direct from global bf16 weights
__device__ __forceinline__ bf16x8 ldb_frag(const unsigned short* W, int row, int rstride, int c) {
    return __builtin_bit_cast(bf16x8, *(const uint4*)(W + (size_t)row * rstride + (size_t)c * 8));
}

// ---------------------------------------------------------------------------
// One-shot weight conversion f32 -> bf16 into workspace (concatenated).
namespace woff {
constexpr unsigned fc1 = 0;
constexpr unsigned ih  = 16384;
constexpr unsigned hh  = 65536;
constexpr unsigned l1  = 114688;
constexpr unsigned l2  = 122880;
constexpr unsigned m1  = 139264;
constexpr unsigned m2  = 204800;
constexpr unsigned kw  = 237568;
constexpr unsigned qw  = 241664;
constexpr unsigned v1  = 243712;
constexpr unsigned v2  = 292864;
constexpr unsigned f2  = 309248;
constexpr unsigned total = 347648;
}

__global__ __launch_bounds__(256)
void wcvt_kernel(const float* __restrict__ fc1_w, const float* __restrict__ w_ih,
                 const float* __restrict__ w_hh, const float* __restrict__ lse_w1,
                 const float* __restrict__ lse_w2, const float* __restrict__ me_w1,
                 const float* __restrict__ me_w2, const float* __restrict__ k_w,
                 const float* __restrict__ q_w, const float* __restrict__ v_w1,
                 const float* __restrict__ v_w2, const float* __restrict__ fc2_w,
                 unsigned short* __restrict__ dst)
{
    unsigned i = blockIdx.x * 256 + threadIdx.x;
    if (i >= woff::total) return;
    const float* src; unsigned base;
    if      (i < woff::ih) { src = fc1_w;  base = woff::fc1; }
    else if (i < woff::hh) { src = w_ih;   base = woff::ih; }
    else if (i < woff::l1) { src = w_hh;   base = woff::hh; }
    else if (i < woff::l2) { src = lse_w1; base = woff::l1; }
    else if (i < woff::m1) { src = lse_w2; base = woff::l2; }
    else if (i < woff::m2) { src = me_w1;  base = woff::m1; }
    else if (i < woff::kw) { src = me_w2;  base = woff::m2; }
    else if (i < woff::qw) { src = k_w;    base = woff::kw; }
    else if (i < woff::v1) { src = q_w;    base = woff::qw; }
    else if (i < woff::v2) { src = v_w1;   base = woff::v1; }
    else if (i < woff::f2) { src = v_w2;   base = woff::v2; }
    else                   { src = fc2_w;  base = woff::f2; }
    dst[i] = (unsigned short)f2bf(src[i - base]);
}

// ---------------------------------------------------------------------------
// Merged stage 1, 64-row tiles, 512 threads / 8 waves, wave w: 16-col strip
// with 4 row-fragments (B-frag reuse x4). (512,4): no spill (r16 verified).
__global__ __launch_bounds__(512, 4)
void stage1(const float* __restrict__ inputs, const float* __restrict__ hidden,
            const unsigned short* __restrict__ fc1w, const float* __restrict__ fc1_b,
            const unsigned short* __restrict__ wih, const unsigned short* __restrict__ whh,
            const float* __restrict__ b_ih, const float* __restrict__ b_hh,
            unsigned short* __restrict__ hb,
            const float* __restrict__ latent,
            const unsigned short* __restrict__ w1b, const float* __restrict__ b1,
            const unsigned short* __restrict__ w2b, const float* __restrict__ b2,
            unsigned short* __restrict__ leb)
{
    __shared__ uint4 shbuf[64 * 48];   // 48 KB, unioned between both paths
    const int tid = threadIdx.x;
    const int lane = tid & 63, w = tid >> 6;      // w: 0..7
    const int m = lane & 15, g = lane >> 4;

    if (blockIdx.x < (unsigned)NB64_) {
        // ================= fc1 + GRU =================
        uint4* Ain   = shbuf;            // 64x16: inputs bf16
        uint4* Atile = shbuf + 64 * 16;  // 64x32: [x | hidden] bf16
        const int r0 = blockIdx.x * 64;

        for (int idx = tid; idx < 64 * 16; idx += 512) {
            int row = idx >> 4, c = idx & 15;
            const float4* p = (const float4*)(inputs + (size_t)(r0 + row) * 128 + c * 8);
            Ain[(row * 16 + c) ^ (row & 7)] = pack8(p[0], p[1]);
            const float4* ph = (const float4*)(hidden + (size_t)(r0 + row) * 128 + c * 8);
            Atile[(row * 32 + (16 + c)) ^ (row & 7)] = pack8(ph[0], ph[1]);
        }
        __syncthreads();

        // ---- phase 1: x = relu(fc1); wave w: cols w*16..w*16+15, 64 rows ----
        {
            f32x4 acc[4] = {};
            #pragma unroll
            for (int ks = 0; ks < 4; ++ks) {
                bf16x8 bf = ldb_frag(fc1w, w * 16 + m, 128, ks * 4 + g);
                #pragma unroll
                for (int fr = 0; fr < 4; ++fr) {
                    bf16x8 af = lda_frag(Ain, 16, fr * 16 + m, ks * 4 + g);
                    acc[fr] = __builtin_amdgcn_mfma_f32_16x16x32_bf16(af, bf, acc[fr], 0, 0, 0);
                }
            }
            int col = w * 16 + m;
            float bv = fc1_b[col];
            int c = col >> 3, el = col & 7;
            #pragma unroll
            for (int fr = 0; fr < 4; ++fr) {
                #pragma unroll
                for (int i = 0; i < 4; ++i) {
                    int row = fr * 16 + g * 4 + i;
                    float v = acc[fr][i] + bv;
                    v = v > 0.f ? v : 0.f;
                    ((unsigned short*)Atile)[((row * 32 + c) ^ (row & 7)) * 8 + el] =
                        (unsigned short)f2bf(v);
                }
            }
        }
        __syncthreads();

        // ---- phase 2: GRU; wave w: gate cols w*16..w*16+15, 64 rows ----
        {
            f32x4 rr[4] = {}, zz[4] = {}, ni[4] = {}, nh[4] = {};
            const int ro = w * 16 + m;
            #pragma unroll
            for (int ks = 0; ks < 4; ++ks) {  // x part: wih
                bf16x8 brr = ldb_frag(wih, ro, 128, ks * 4 + g);
                bf16x8 bzz = ldb_frag(wih, 128 + ro, 128, ks * 4 + g);
                bf16x8 bnn = ldb_frag(wih, 256 + ro, 128, ks * 4 + g);
                #pragma unroll
                for (int fr = 0; fr < 4; ++fr) {
                    bf16x8 af = lda_frag(Atile, 32, fr * 16 + m, ks * 4 + g);
                    rr[fr] = __builtin_amdgcn_mfma_f32_16x16x32_bf16(af, brr, rr[fr], 0, 0, 0);
                    zz[fr] = __builtin_amdgcn_mfma_f32_16x16x32_bf16(af, bzz, zz[fr], 0, 0, 0);
                    ni[fr] = __builtin_amdgcn_mfma_f32_16x16x32_bf16(af, bnn, ni[fr], 0, 0, 0);
                }
            }
            #pragma unroll
            for (int ks = 0; ks < 4; ++ks) {  // hidden part: whh
                bf16x8 brr = ldb_frag(whh, ro, 128, ks * 4 + g);
                bf16x8 bzz = ldb_frag(whh, 128 + ro, 128, ks * 4 + g);
                bf16x8 bnn = ldb_frag(whh, 256 + ro, 128, ks * 4 + g);
                #pragma unroll
                for (int fr = 0; fr < 4; ++fr) {
                    bf16x8 af = lda_frag(Atile, 32, fr * 16 + m, 16 + ks * 4 + g);
                    rr[fr] = __builtin_amdgcn_mfma_f32_16x16x32_bf16(af, brr, rr[fr], 0, 0, 0);
                    zz[fr] = __builtin_amdgcn_mfma_f32_16x16x32_bf16(af, bzz, zz[fr], 0, 0, 0);
                    nh[fr] = __builtin_amdgcn_mfma_f32_16x16x32_bf16(af, bnn, nh[fr], 0, 0, 0);
                }
            }
            {
                int c = ro;   // 0..127
                float brz = b_ih[c] + b_hh[c];
                float bzz2 = b_ih[128 + c] + b_hh[128 + c];
                float bin = b_ih[256 + c], bhn = b_hh[256 + c];
                int hc = 16 + (c >> 3), hel = c & 7;  // hidden chunk in Atile
                #pragma unroll
                for (int fr = 0; fr < 4; ++fr) {
                    #pragma unroll
                    for (int i = 0; i < 4; ++i) {
                        int row = fr * 16 + g * 4 + i;
                        float rv = fsig(rr[fr][i] + brz);
                        float zv = fsig(zz[fr][i] + bzz2);
                        float ng = ftanh(ni[fr][i] + bin + rv * (nh[fr][i] + bhn));
                        float hp = bf2f(((unsigned short*)Atile)[((row * 32 + hc) ^ (row & 7)) * 8 + hel]);
                        float hv = ng + zv * (hp - ng);
                        hb[(size_t)(r0 + row) * 128 + c] = (unsigned short)f2bf(hv);
                    }
                }
            }
        }
    } else {
        // ================= lse1 + lse2 =================
        uint4* Alat = shbuf;            // 64x8
        uint4* Alt  = shbuf + 64 * 8;   // 64x16
        const int r0 = (blockIdx.x - NB64_) * 64;

        {   // 512 items, one per thread
            int row = tid >> 3, c = tid & 7;
            const float4* p = (const float4*)(latent + (size_t)(r0 + row) * 64 + c * 8);
            Alat[(row * 8 + c) ^ (row & 7)] = pack8(p[0], p[1]);
        }
        __syncthreads();

        // lse1: K=64, O=128; wave w: cols w*16 -> Alt
        {
            f32x4 acc[4] = {};
            #pragma unroll
            for (int ks = 0; ks < 2; ++ks) {
                bf16x8 bf = ldb_frag(w1b, w * 16 + m, 64, ks * 4 + g);
                #pragma unroll
                for (int fr = 0; fr < 4; ++fr) {
                    bf16x8 af = lda_frag(Alat, 8, fr * 16 + m, ks * 4 + g);
                    acc[fr] = __builtin_amdgcn_mfma_f32_16x16x32_bf16(af, bf, acc[fr], 0, 0, 0);
                }
            }
            int col = w * 16 + m;
            float bv = b1[col];
            int c = col >> 3, el = col & 7;
            #pragma unroll
            for (int fr = 0; fr < 4; ++fr) {
                #pragma unroll
                for (int i = 0; i < 4; ++i) {
                    int row = fr * 16 + g * 4 + i;
                    float v = acc[fr][i] + bv;
                    v = v > 0.f ? v : 0.f;
                    ((unsigned short*)Alt)[((row * 16 + c) ^ (row & 7)) * 8 + el] =
                        (unsigned short)f2bf(v);
                }
            }
        }
        __syncthreads();

        // lse2: K=128, O=128 -> leb
        {
            f32x4 acc[4] = {};
            #pragma unroll
            for (int ks = 0; ks < 4; ++ks) {
                bf16x8 bf = ldb_frag(w2b, w * 16 + m, 128, ks * 4 + g);
                #pragma unroll
                for (int fr = 0; fr < 4; ++fr) {
                    bf16x8 af = lda_frag(Alt, 16, fr * 16 + m, ks * 4 + g);
                    acc[fr] = __builtin_amdgcn_mfma_f32_16x16x32_bf16(af, bf, acc[fr], 0, 0, 0);
                }
            }
            int col = w * 16 + m;
            float bv = b2[col];
            #pragma unroll
            for (int fr = 0; fr < 4; ++fr) {
                #pragma unroll
                for (int i = 0; i < 4; ++i) {
                    int rowl = fr * 16 + g * 4 + i;
                    float v = acc[fr][i] + bv;
                    leb[(size_t)(r0 + rowl) * 128 + col] = (unsigned short)f2bf(v);
                }
            }
        }
    }
}

// ---------------------------------------------------------------------------
// me1 GEMM (K=256, O=256) + BN partials + fused hl, 64-row blocks, 512 thr.
__global__ __launch_bounds__(512, 4)
void me1_stats(const unsigned short* __restrict__ hb, const unsigned short* __restrict__ leb,
               const unsigned short* __restrict__ W, const float* __restrict__ bias,
               const unsigned short* __restrict__ f2w, const float* __restrict__ fc2_b,
               unsigned short* __restrict__ t1,
               float* __restrict__ psum, float* __restrict__ psq,
               float* __restrict__ hl)
{
    __shared__ uint4 Atile[64 * 32];   // 32 KB: [h | le]
    __shared__ uint4 T1b[64 * 32];     // 32 KB: t1 bounce (linear 64x256 bf16)
    const int tid = threadIdx.x;
    const int r0 = blockIdx.x * 64;

    for (int idx = tid; idx < 64 * 16; idx += 512) {
        int row = idx >> 4, c = idx & 15;
        Atile[(row * 32 + c) ^ (row & 7)] =
            *(const uint4*)(hb + (size_t)(r0 + row) * 128 + c * 8);
        Atile[(row * 32 + (16 + c)) ^ (row & 7)] =
            *(const uint4*)(leb + (size_t)(r0 + row) * 128 + c * 8);
    }
    __syncthreads();

    const int lane = tid & 63, w = tid >> 6;
    const int m = lane & 15, g = lane >> 4;
    unsigned short* t1s = (unsigned short*)T1b;

    {
        const int o0 = w * 32;
        f32x4 acc[4][2] = {};
        #pragma unroll
        for (int ks = 0; ks < 8; ++ks) {
            bf16x8 bf[2];
            #pragma unroll
            for (int fc = 0; fc < 2; ++fc)
                bf[fc] = ldb_frag(W, o0 + fc * 16 + m, 256, ks * 4 + g);
            #pragma unroll
            for (int fr = 0; fr < 4; ++fr) {
                bf16x8 af = lda_frag(Atile, 32, fr * 16 + m, ks * 4 + g);
                #pragma unroll
                for (int fc = 0; fc < 2; ++fc)
                    acc[fr][fc] = __builtin_amdgcn_mfma_f32_16x16x32_bf16(
                        af, bf[fc], acc[fr][fc], 0, 0, 0);
            }
        }
        #pragma unroll
        for (int fc = 0; fc < 2; ++fc) {
            int col = o0 + fc * 16 + m;
            float bv = bias[col];
            float s = 0.f, q = 0.f;
            #pragma unroll
            for (int fr = 0; fr < 4; ++fr) {
                #pragma unroll
                for (int i = 0; i < 4; ++i) {
                    int rowl = fr * 16 + g * 4 + i;
                    float v = acc[fr][fc][i] + bv;
                    t1s[rowl * 256 + col] = (unsigned short)f2bf(v);
                    s += v; q += v * v;
                }
            }
            s += __shfl_xor(s, 16); s += __shfl_xor(s, 32);  // over g: all 64 rows
            q += __shfl_xor(q, 16); q += __shfl_xor(q, 32);
            if (lane < 16) {
                psum[(size_t)blockIdx.x * 256 + col] = s;
                psq[(size_t)blockIdx.x * 256 + col] = q;
            }
        }
    }
    __syncthreads();
    for (int idx = tid; idx < 64 * 32; idx += 512) {  // coalesced t1 store
        int row = idx >> 5, c = idx & 31;
        *(uint4*)(t1 + (size_t)(r0 + row) * 256 + c * 8) = T1b[row * 32 + c];
    }

    // ---- fused hl: waves 0-3, rows w*16..w*16+15, cols 0..29 ----
    if (w < 4) {
        f32x4 acc[2] = {};
        #pragma unroll
        for (int ks = 0; ks < 8; ++ks) {
            bf16x8 af = lda_frag(Atile, 32, w * 16 + m, ks * 4 + g);
            bf16x8 bf[2];
            #pragma unroll
            for (int fc = 0; fc < 2; ++fc) {
                int col = fc * 16 + m;
                bf[fc] = (col < NA_) ? ldb_frag(f2w, col, 1280, ks * 4 + g) : bf16x8{};
            }
            #pragma unroll
            for (int fc = 0; fc < 2; ++fc)
                acc[fc] = __builtin_amdgcn_mfma_f32_16x16x32_bf16(af, bf[fc], acc[fc], 0, 0, 0);
        }
        #pragma unroll
        for (int fc = 0; fc < 2; ++fc) {
            int col = fc * 16 + m;
            if (col < NA_) {
                float bv = fc2_b[col];
                #pragma unroll
                for (int i = 0; i < 4; ++i) {
                    int row = r0 + w * 16 + g * 4 + i;
                    hl[(size_t)row * NA_ + col] = acc[fc][i] + bv;
                }
            }
        }
    }
}

// ---------------------------------------------------------------------------
// Parallel BN finalize: one block per feature; threads stride over NB64_.
__global__ __launch_bounds__(256)
void bn_final_kernel(const float* __restrict__ psum, const float* __restrict__ psq,
                     const float* __restrict__ g, const float* __restrict__ beta,
                     float* __restrict__ scale, float* __restrict__ shift)
{
    __shared__ float redS[4], redQ[4];
    const int f = blockIdx.x;
    const int tid = threadIdx.x;
    float s = 0.f, q = 0.f;
    for (int b = tid; b < NB64_; b += 256) {
        s += psum[(size_t)b * 256 + f];
        q += psq[(size_t)b * 256 + f];
    }
    #pragma unroll
    for (int off = 32; off >= 1; off >>= 1) {
        s += __shfl_down(s, off);
        q += __shfl_down(q, off);
    }
    if ((tid & 63) == 0) { redS[tid >> 6] = s; redQ[tid >> 6] = q; }
    __syncthreads();
    if (tid == 0) {
        s = redS[0] + redS[1] + redS[2] + redS[3];
        q = redQ[0] + redQ[1] + redQ[2] + redQ[3];
        float mean = s / (float)R_;
        float var = q / (float)R_ - mean * mean;
        float istd = rsqrtf(var + 1e-5f);
        float sc = g[f] * istd;
        scale[f] = sc;
        shift[f] = beta[f] - mean * sc;
    }
}

// ---------------------------------------------------------------------------
// Fused me2 + kq_norm + v1 + v2, 64-row blocks, 512 threads / 8 waves.
// kh/qh stored as bf16 (halves kq traffic; unit-norm vectors, error << thr).
__global__ __launch_bounds__(512, 4)
void me2kqv(const unsigned short* __restrict__ t1,
            const float* __restrict__ scale, const float* __restrict__ shift,
            const unsigned short* __restrict__ W2, const float* __restrict__ me2_b,
            const float* __restrict__ eps,
            const unsigned short* __restrict__ hb,
            const unsigned short* __restrict__ kwb, const float* __restrict__ k_b,
            const unsigned short* __restrict__ qwb, const float* __restrict__ q_b,
            const unsigned short* __restrict__ v1w, const float* __restrict__ v1_b,
            const unsigned short* __restrict__ v2w, const float* __restrict__ v2_b,
            unsigned short* __restrict__ kh, unsigned short* __restrict__ qh,
            unsigned short* __restrict__ valb)
{
    __shared__ uint4 bufA[64 * 32];   // 32 KB: t1(BN) -> mean scratch -> A3 (t3)
    __shared__ uint4 bufB[64 * 24];   // 24 KB: [h 0..15 | pm 16..23] -> val bounce
    __shared__ float sc_s[256], sh_s[256];
    const int tid = threadIdx.x;
    const int r0 = blockIdx.x * 64;
    const int lane = tid & 63, w = tid >> 6;   // w: 0..7
    const int m = lane & 15, g = lane >> 4;

    if (tid < 256) { sc_s[tid] = scale[tid]; sh_s[tid] = shift[tid]; }
    for (int idx = tid; idx < 64 * 16; idx += 512) {
        int row = idx >> 4, c = idx & 15;
        bufB[(row * 24 + c) ^ (row & 7)] =
            *(const uint4*)(hb + (size_t)(r0 + row) * 128 + c * 8);
    }
    __syncthreads();

    // stage t1 with BN(scale/shift)+lrelu -> bufA (swizzled)
    for (int idx = tid; idx < 64 * 32; idx += 512) {
        int row = idx >> 5, c = idx & 31;
        uint4 u = *(const uint4*)(t1 + (size_t)(r0 + row) * 256 + c * 8);
        unsigned int vv[4] = {u.x, u.y, u.z, u.w};
        float f[8];
        #pragma unroll
        for (int q2 = 0; q2 < 4; ++q2) {
            f[2 * q2]     = __uint_as_float((vv[q2] & 0xffffu) << 16);
            f[2 * q2 + 1] = __uint_as_float(vv[q2] & 0xffff0000u);
        }
        int k = c * 8;
        #pragma unroll
        for (int j = 0; j < 8; ++j) {
            float v = f[j] * sc_s[k + j] + sh_s[k + j];
            f[j] = v > 0.f ? v : 0.01f * v;
        }
        uint4 r;
        r.x = pack2(f[0], f[1]); r.y = pack2(f[2], f[3]);
        r.z = pack2(f[4], f[5]); r.w = pack2(f[6], f[7]);
        bufA[(row * 32 + c) ^ (row & 7)] = r;
    }
    __syncthreads();

    // ---- me2 GEMM: wave w owns output col w*16+m (0..127); 4 row frags ----
    {
        const int colm = w * 16 + m;       // 0..63 mean, 64..127 std
        f32x4 acc[4] = {};
        #pragma unroll
        for (int ks = 0; ks < 8; ++ks) {
            bf16x8 bf = ldb_frag(W2, colm, 256, ks * 4 + g);
            #pragma unroll
            for (int fr = 0; fr < 4; ++fr) {
                bf16x8 af = lda_frag(bufA, 32, fr * 16 + m, ks * 4 + g);
                acc[fr] = __builtin_amdgcn_mfma_f32_16x16x32_bf16(af, bf, acc[fr], 0, 0, 0);
            }
        }
        float bv = me2_b[colm];
        __syncthreads();   // all bufA (t1) reads done; reuse as f32 mean scratch
        float* meanS = (float*)bufA;       // [64][64] f32
        if (w < 4) {       // mean cols: clip(lrelu(.)) -> scratch
            #pragma unroll
            for (int fr = 0; fr < 4; ++fr) {
                #pragma unroll
                for (int i = 0; i < 4; ++i) {
                    int row = fr * 16 + g * 4 + i;
                    float vm = acc[fr][i] + bv;
                    vm = vm > 0.f ? vm : 0.01f * vm;
                    vm = fminf(fmaxf(vm, -1.f), 1.f);
                    meanS[row * 64 + colm] = vm;
                }
            }
        }
        __syncthreads();
        if (w >= 4) {      // std cols: combine with mean + eps -> pm in bufB
            int cp = colm - 64;            // 0..63
            int hc = 16 + (cp >> 3), hel = cp & 7;
            #pragma unroll
            for (int fr = 0; fr < 4; ++fr) {
                #pragma unroll
                for (int i = 0; i < 4; ++i) {
                    int row = fr * 16 + g * 4 + i;
                    float vs = acc[fr][i] + bv;
                    vs = vs > 0.f ? vs : 0.01f * vs;
                    vs = fminf(fmaxf(vs, 0.5f), 1.f);
                    float e = eps[(size_t)(r0 + row) * 64 + cp];
                    float vm = meanS[row * 64 + cp];
                    ((unsigned short*)bufB)[((row * 24 + hc) ^ (row & 7)) * 8 + hel] =
                        (unsigned short)f2bf(vm + vs * e);
                }
            }
        }
    }
    __syncthreads();   // pm visible in bufB; meanS consumed (bufA free for A3)

    // ---- kq-norm: waves 0-3. w0: kh rows 0-31, w1: kh rows 32-63,
    //      w2: qh rows 0-31, w3: qh rows 32-63. Store bf16.
    if (w < 4) {
        const bool isq = (w >= 2);
        const int rbase = (w & 1) * 32;
        f32x4 acc[2][2] = {};
        const int nks = isq ? 2 : 4;
        for (int ks = 0; ks < nks; ++ks) {
            bf16x8 af[2], bf[2];
            #pragma unroll
            for (int fr = 0; fr < 2; ++fr)
                af[fr] = lda_frag(bufB, 24, rbase + fr * 16 + m, (isq ? 16 : 0) + ks * 4 + g);
            #pragma unroll
            for (int fc = 0; fc < 2; ++fc)
                bf[fc] = isq ? ldb_frag(qwb, fc * 16 + m, 64, ks * 4 + g)
                             : ldb_frag(kwb, fc * 16 + m, 128, ks * 4 + g);
            #pragma unroll
            for (int fr = 0; fr < 2; ++fr)
                #pragma unroll
                for (int fc = 0; fc < 2; ++fc)
                    acc[fr][fc] = __builtin_amdgcn_mfma_f32_16x16x32_bf16(
                        af[fr], bf[fc], acc[fr][fc], 0, 0, 0);
        }
        const float* bias = isq ? q_b : k_b;
        float b0 = bias[m], b1 = bias[16 + m];
        unsigned short* outp = isq ? qh : kh;
        #pragma unroll
        for (int fr = 0; fr < 2; ++fr) {
            #pragma unroll
            for (int i = 0; i < 4; ++i) {
                float v0 = acc[fr][0][i] + b0;
                float v1 = acc[fr][1][i] + b1;
                float ss = v0 * v0 + v1 * v1;
                ss += __shfl_xor(ss, 1); ss += __shfl_xor(ss, 2);
                ss += __shfl_xor(ss, 4); ss += __shfl_xor(ss, 8);
                float inv = 1.f / fmaxf(sqrtf(ss), 1e-8f);
                int row = r0 + rbase + fr * 16 + g * 4 + i;
                outp[(size_t)row * 32 + m] = (unsigned short)f2bf(v0 * inv);
                outp[(size_t)row * 32 + 16 + m] = (unsigned short)f2bf(v1 * inv);
            }
        }
    }

    // ---- v1 (K=192, O=256): 8 waves x 32 cols, 4 row frags -> bufA as A3 ----
    {
        const int o0 = w * 32;
        f32x4 acc[4][2] = {};
        #pragma unroll
        for (int ks = 0; ks < 6; ++ks) {
            bf16x8 bf[2];
            #pragma unroll
            for (int fc = 0; fc < 2; ++fc)
                bf[fc] = ldb_frag(v1w, o0 + fc * 16 + m, 192, ks * 4 + g);
            #pragma unroll
            for (int fr = 0; fr < 4; ++fr) {
                bf16x8 af = lda_frag(bufB, 24, fr * 16 + m, ks * 4 + g);
                #pragma unroll
                for (int fc = 0; fc < 2; ++fc)
                    acc[fr][fc] = __builtin_amdgcn_mfma_f32_16x16x32_bf16(
                        af, bf[fc], acc[fr][fc], 0, 0, 0);
            }
        }
        #pragma unroll
        for (int fc = 0; fc < 2; ++fc) {
            int col = o0 + fc * 16 + m;
            float bv = v1_b[col];
            int c = col >> 3, el = col & 7;
            #pragma unroll
            for (int fr = 0; fr < 4; ++fr) {
                #pragma unroll
                for (int i = 0; i < 4; ++i) {
                    int row = fr * 16 + g * 4 + i;
                    float v = acc[fr][fc][i] + bv;
                    v = v > 0.f ? v : 0.01f * v;
                    ((unsigned short*)bufA)[((row * 32 + c) ^ (row & 7)) * 8 + el] =
                        (unsigned short)f2bf(v);
                }
            }
        }
    }
    __syncthreads();

    // ---- v2 (K=256, O=64): wave w: col (w&3)*16+m, rows (w>>2)*32.. ----
    {
        const int col = (w & 3) * 16 + m;
        const int rbase = (w >> 2) * 32;
        f32x4 acc[2] = {};
        #pragma unroll
        for (int ks = 0; ks < 8; ++ks) {
            bf16x8 bf = ldb_frag(v2w, col, 256, ks * 4 + g);
            #pragma unroll
            for (int fr = 0; fr < 2; ++fr) {
                bf16x8 af = lda_frag(bufA, 32, rbase + fr * 16 + m, ks * 4 + g);
                acc[fr] = __builtin_amdgcn_mfma_f32_16x16x32_bf16(af, bf, acc[fr], 0, 0, 0);
            }
        }
        float bv = v2_b[col];
        unsigned short* vb = (unsigned short*)bufB;  // bufB dead after v1
        #pragma unroll
        for (int fr = 0; fr < 2; ++fr) {
            #pragma unroll
            for (int i = 0; i < 4; ++i) {
                int rowl = rbase + fr * 16 + g * 4 + i;
                vb[rowl * 64 + col] = (unsigned short)f2bf(acc[fr][i] + bv);
            }
        }
    }
    __syncthreads();
    {   // 64x64 bf16 = 512 uint4: one per thread
        int row = tid >> 3, c = tid & 7;
        *(uint4*)(valb + (size_t)(r0 + row) * 64 + c * 8) = ((uint4*)bufB)[row * 8 + c];
    }
}

// ---------------------------------------------------------------------------
// MFMA-ized tail: logits+softmax (1 MFMA/batch) + vproj (4 MFMA/agent, bf16
// w2 slice from L2) + combine -> out. 8 batches (128 rows) per block.
__global__ __launch_bounds__(512, 4)
void attn_tail(const unsigned short* __restrict__ khb, const unsigned short* __restrict__ qhb,
               const unsigned short* __restrict__ valb,
               const unsigned short* __restrict__ f2wb,   // bf16 fc2_w, stride 1280
               const float* __restrict__ hl, float* __restrict__ outv)
{
    __shared__ uint4 vt[136 * 8];        // value transposed by agent: [j*8+bi][8 chunks]
    __shared__ float al[128 * 16];       // alpha[row in block][j]
    __shared__ float vp[128 * 32];       // vproj[(j*8+bi)][na]
    const int tid = threadIdx.x;
    const int b0 = blockIdx.x * 8;       // first batch
    const size_t r0 = (size_t)b0 * 16;   // first row
    const int lane = tid & 63, w = tid >> 6;   // w: 0..7
    const int m = lane & 15, g = lane >> 4;

    // stage value transposed: src row r = bi*16 + j  ->  vt row j*8 + bi
    for (int idx = tid; idx < 128 * 8; idx += 512) {
        int r = idx >> 3, c = idx & 7;
        int bi = r >> 4, j = r & 15;
        int vr = j * 8 + bi;
        vt[(vr * 8 + c) ^ (vr & 7)] = *(const uint4*)(valb + (r0 + r) * 64 + c * 8);
    }

    // logits via MFMA: wave w handles batch b0+w. A=kh rows, B=qh rows (K=32).
    {
        bf16x8 af = ldb_frag(khb, (b0 + w) * 16 + m, 32, g);
        bf16x8 bf = ldb_frag(qhb, (b0 + w) * 16 + m, 32, g);
        f32x4 acc = {};
        acc = __builtin_amdgcn_mfma_f32_16x16x32_bf16(af, bf, acc, 0, 0, 0);
        // lane(m,g) holds logits[i' = g*4+i][j' = m]
        #pragma unroll
        for (int i = 0; i < 4; ++i) {
            float l = acc[i];
            float mx = l;
            #pragma unroll
            for (int mm = 8; mm >= 1; mm >>= 1) mx = fmaxf(mx, __shfl_xor(mx, mm));
            float e = __expf(l - mx);
            float s = e;
            #pragma unroll
            for (int mm = 8; mm >= 1; mm >>= 1) s += __shfl_xor(s, mm);
            float a = e / s;
            int ip = g * 4 + i;
            if (ip == m) a = 0.f;
            al[(w * 16 + ip) * 16 + m] = a;
        }
    }
    __syncthreads();

    // vproj via MFMA: wave w handles agents j = w and j = w+8.
    #pragma unroll
    for (int jj = 0; jj < 2; ++jj) {
        int j = w + jj * 8;
        f32x4 acc[2] = {};
        #pragma unroll
        for (int ks = 0; ks < 2; ++ks) {
            bf16x8 af = lda_frag(vt, 8, j * 8 + (m & 7), ks * 4 + g);
            #pragma unroll
            for (int fc = 0; fc < 2; ++fc) {
                bf16x8 bf = ldb_frag(f2wb, fc * 16 + m, 1280, 32 + j * 8 + ks * 4 + g);
                acc[fc] = __builtin_amdgcn_mfma_f32_16x16x32_bf16(af, bf, acc[fc], 0, 0, 0);
            }
        }
        #pragma unroll
        for (int fc = 0; fc < 2; ++fc) {
            int na = fc * 16 + m;
            if (na < NA_) {
                #pragma unroll
                for (int i = 0; i < 4; ++i) {
                    int bi = g * 4 + i;
                    if (bi < 8) vp[(j * 8 + bi) * 32 + na] = acc[fc][i];
                }
            }
        }
    }
    __syncthreads();

    // combine: out[r0+row][na] = hl + sum_j al[row][j] * vp[j*8+bi][na]
    for (int task = tid; task < 128 * NA_; task += 512) {
        int row = task / NA_, na = task - row * NA_;
        int bi = row >> 4;
        float acc = hl[(r0 + row) * NA_ + na];
        #pragma unroll
        for (int j = 0; j < 16; ++j)
            acc = fmaf(al[row * 16 + j], vp[(j * 8 + bi) * 32 + na], acc);
        outv[(r0 + row) * NA_ + na] = acc;
    }
}

extern "C" void kernel_launch(void* const* d_in, const int* in_sizes, int n_in,
                              void* d_out, int out_size, void* d_ws, size_t ws_size,
                              hipStream_t stream)
{
    (void)in_sizes; (void)n_in; (void)out_size; (void)ws_size;
    const float* inputs  = (const float*)d_in[0];
    const float* hidden  = (const float*)d_in[1];
    const float* latent  = (const float*)d_in[2];
    const float* eps     = (const float*)d_in[3];
    const float* fc1_w   = (const float*)d_in[4];
    const float* fc1_b   = (const float*)d_in[5];
    const float* w_ih    = (const float*)d_in[6];
    const float* w_hh    = (const float*)d_in[7];
    const float* b_ih    = (const float*)d_in[8];
    const float* b_hh    = (const float*)d_in[9];
    const float* lse_w1  = (const float*)d_in[10];
    const float* lse_b1  = (const float*)d_in[11];
    const float* lse_w2  = (const float*)d_in[12];
    const float* lse_b2  = (const float*)d_in[13];
    const float* me_w1   = (const float*)d_in[14];
    const float* me_b1   = (const float*)d_in[15];
    const float* me_g    = (const float*)d_in[16];
    const float* me_beta = (const float*)d_in[17];
    const float* me_w2   = (const float*)d_in[18];
    const float* me_b2   = (const float*)d_in[19];
    const float* k_w     = (const float*)d_in[20];
    const float* k_b     = (const float*)d_in[21];
    const float* q_w     = (const float*)d_in[22];
    const float* q_b     = (const float*)d_in[23];
    const float* v_w1    = (const float*)d_in[24];
    const float* v_b1    = (const float*)d_in[25];
    const float* v_w2    = (const float*)d_in[26];
    const float* v_b2    = (const float*)d_in[27];
    const float* fc2_w   = (const float*)d_in[28];
    const float* fc2_b   = (const float*)d_in[29];

    const size_t R = R_;
    // Workspace layout: bf16 activations, bf16 weights, then f32 buffers.
    unsigned short* bws = (unsigned short*)d_ws;
    unsigned short* hb   = bws;               // R*128
    unsigned short* leb  = hb + R * 128;      // R*128
    unsigned short* t1b  = leb + R * 128;     // R*256
    unsigned short* valb = t1b + R * 256;     // R*64
    unsigned short* khb  = valb + R * 64;     // R*32 (bf16)
    unsigned short* qhb  = khb + R * 32;      // R*32 (bf16)
    unsigned short* wb   = qhb + R * 32;      // 347648 (bf16 weights)
    float* fws  = (float*)(wb + woff::total);
    float* hlf  = fws;                 // R*30
    float* psum = hlf + R * 30;        // NB64_*256
    float* psq  = psum + (size_t)NB64_ * 256;
    float* scale = psq + (size_t)NB64_ * 256;
    float* shift = scale + 256;

    dim3 blk(256);
    dim3 g512(NB64_);

    // 0) weights -> bf16 (once per call; cheap)
    wcvt_kernel<<<dim3((woff::total + 255) / 256), blk, 0, stream>>>(
        fc1_w, w_ih, w_hh, lse_w1, lse_w2, me_w1, me_w2, k_w, q_w, v_w1, v_w2, fc2_w, wb);

    // 1) merged stage1 (64-row, 512 thr): fc1+GRU (0..511), lse1+lse2 (512..1023)
    stage1<<<dim3(2 * NB64_), dim3(512), 0, stream>>>(
        inputs, hidden, wb + woff::fc1, fc1_b, wb + woff::ih, wb + woff::hh,
        b_ih, b_hh, hb,
        latent, wb + woff::l1, lse_b1, wb + woff::l2, lse_b2, leb);
    // 2) t1 = me1(cat(h,le)) + BN partials + hl (64-row, 512 thr)
    me1_stats<<<g512, dim3(512), 0, stream>>>(hb, leb, wb + woff::m1, me_b1,
                                              wb + woff::f2, fc2_b, t1b, psum, psq, hlf);
    // 2b) BN finalize (parallel: one block per feature)
    bn_final_kernel<<<dim3(256), blk, 0, stream>>>(psum, psq, me_g, me_beta, scale, shift);
    // 3) fused me2 -> pm [LDS] -> kq_norm + v1 + v2 (64-row, 512 thr)
    me2kqv<<<g512, dim3(512), 0, stream>>>(t1b, scale, shift, wb + woff::m2, me_b2, eps,
                                           hb, wb + woff::kw, k_b, wb + woff::qw, q_b,
                                           wb + woff::v1, v_b1, wb + woff::v2, v_b2,
                                           khb, qhb, valb);
    // 4) MFMA-ized tail: logits+softmax + vproj + combine -> out (8 batches/block)
    attn_tail<<<dim3(BSB_ / 8), dim3(512), 0, stream>>>(
        khb, qhb, valb, wb + woff::f2, hlf, (float*)d_out);
}